// Round 8
// baseline (173.845 us; speedup 1.0000x reference)
//
#include <hip/hip_runtime.h>

// GAT forward: bf16-MFMA projections fused with edge-count, CSR scan,
// scatter, fused score+softmax+aggregate (32-lane/edge ushort8 gather).
// N=50000, E=800000, IN_DIM=128, H=8, D=16.

#define NEG_SLOPE 0.2f
#define CB 1024   // count-role blocks fused into proj kernel

typedef __attribute__((ext_vector_type(8))) short short8;   // 8 bf16
typedef __attribute__((ext_vector_type(4))) float f32x4;    // MFMA C/D frag

__device__ __forceinline__ unsigned short f2bf(float f) {
    unsigned int u = __builtin_bit_cast(unsigned int, f);
    u = (u + 0x7fffu + ((u >> 16) & 1u)) >> 16;   // RNE
    return (unsigned short)u;
}
__device__ __forceinline__ float bf2f(unsigned short s) {
    unsigned int u = (unsigned int)s << 16;
    return __builtin_bit_cast(float, u);
}

// ---------------------------------------------------------------------------
// Kernel 1: zero cnt + pack weights to MFMA-fragment-linear bf16.
// ---------------------------------------------------------------------------
__global__ __launch_bounds__(256) void zero_wconv_kernel(
    const float* __restrict__ Wq, const float* __restrict__ Wk,
    const float* __restrict__ Wv, const float* __restrict__ Wres,
    unsigned short* __restrict__ wpk, int* __restrict__ cnt, int n4)
{
    int t = blockIdx.x * 256 + threadIdx.x;
    if (t < 8192) {
        int l = t & 63;
        int v = t >> 6;
        int kk = v & 3;
        int wct = v >> 2;
        int ct = wct & 7;
        int w = wct >> 3;
        const float* W = (w == 0) ? Wq : (w == 1) ? Wk : (w == 2) ? Wv : Wres;
        const float* srcp = W + (size_t)(ct * 16 + (l & 15)) * 128 + kk * 32 + (l >> 4) * 8;
        float4 lo = *reinterpret_cast<const float4*>(srcp);
        float4 hi = *reinterpret_cast<const float4*>(srcp + 4);
        short8 o;
        o[0] = (short)f2bf(lo.x); o[1] = (short)f2bf(lo.y);
        o[2] = (short)f2bf(lo.z); o[3] = (short)f2bf(lo.w);
        o[4] = (short)f2bf(hi.x); o[5] = (short)f2bf(hi.y);
        o[6] = (short)f2bf(hi.z); o[7] = (short)f2bf(hi.w);
        *reinterpret_cast<short8*>(wpk + (size_t)t * 8) = o;
    } else {
        int u = t - 8192;
        if (u < n4) reinterpret_cast<int4*>(cnt)[u] = make_int4(0, 0, 0, 0);
    }
}

// ---------------------------------------------------------------------------
// Kernel 2: MFMA projections + fused edge-count.
// kv layout: kv[n][2c+0] = k[n][c], kv[n][2c+1] = v[n][c]  (c = 0..127)
// ---------------------------------------------------------------------------
__global__ __launch_bounds__(256) void proj_count_kernel(
    const float* __restrict__ h,
    const unsigned short* __restrict__ wpk,
    unsigned short* __restrict__ qb, unsigned short* __restrict__ kvb,
    float* __restrict__ res,
    const int* __restrict__ dst, int* __restrict__ cnt,
    int N, int E, int PB)
{
    if (blockIdx.x >= PB) {
        int start = (blockIdx.x - PB) * 256 + threadIdx.x;
        for (int e = start; e < E; e += CB * 256)
            atomicAdd(&cnt[dst[e]], 1);
        return;
    }

    const int wid = threadIdx.x >> 6;
    const int lane = threadIdx.x & 63;
    const int row0 = blockIdx.x * 128 + wid * 32;
    const int r = lane & 15, g = lane >> 4;

    short8 afrag[2][4];
    #pragma unroll
    for (int grp = 0; grp < 2; ++grp) {
        int arow = row0 + grp * 16 + r;
        if (arow >= N) arow = N - 1;
        const float* hrow = h + (size_t)arow * 128 + g * 8;
        #pragma unroll
        for (int kk = 0; kk < 4; ++kk) {
            float4 lo = *reinterpret_cast<const float4*>(hrow + kk * 32);
            float4 hi = *reinterpret_cast<const float4*>(hrow + kk * 32 + 4);
            short8 a;
            a[0] = (short)f2bf(lo.x); a[1] = (short)f2bf(lo.y);
            a[2] = (short)f2bf(lo.z); a[3] = (short)f2bf(lo.w);
            a[4] = (short)f2bf(hi.x); a[5] = (short)f2bf(hi.y);
            a[6] = (short)f2bf(hi.z); a[7] = (short)f2bf(hi.w);
            afrag[grp][kk] = a;
        }
    }

    for (int w = 0; w < 4; ++w) {
        f32x4 acc[2][8];
        #pragma unroll
        for (int grp = 0; grp < 2; ++grp)
            #pragma unroll
            for (int ct = 0; ct < 8; ++ct) acc[grp][ct] = (f32x4)(0.f);

        #pragma unroll
        for (int ct = 0; ct < 8; ++ct) {
            const unsigned short* bp =
                wpk + ((size_t)((w * 8 + ct) * 4) * 64 + lane) * 8;
            short8 bfrag[4];
            #pragma unroll
            for (int kk = 0; kk < 4; ++kk)
                bfrag[kk] = *reinterpret_cast<const short8*>(bp + (size_t)kk * 512);
            #pragma unroll
            for (int grp = 0; grp < 2; ++grp)
                #pragma unroll
                for (int kk = 0; kk < 4; ++kk)
                    acc[grp][ct] = __builtin_amdgcn_mfma_f32_16x16x32_bf16(
                        afrag[grp][kk], bfrag[kk], acc[grp][ct], 0, 0, 0);
        }

        #pragma unroll
        for (int grp = 0; grp < 2; ++grp) {
            #pragma unroll
            for (int j = 0; j < 4; ++j) {
                int orow = row0 + grp * 16 + g * 4 + j;
                if (orow < N) {
                    if (w == 0) {
                        #pragma unroll
                        for (int ct = 0; ct < 8; ++ct)
                            qb[(size_t)orow * 128 + ct * 16 + r] = f2bf(acc[grp][ct][j]);
                    } else if (w == 3) {
                        #pragma unroll
                        for (int ct = 0; ct < 8; ++ct)
                            res[(size_t)orow * 128 + ct * 16 + r] = acc[grp][ct][j];
                    } else {
                        // kv element interleave: col c -> idx 2c + (k?0:1)
                        const int voff = (w == 2) ? 1 : 0;
                        #pragma unroll
                        for (int ct = 0; ct < 8; ++ct) {
                            int idx = ct * 32 + 2 * r + voff;
                            kvb[(size_t)orow * 256 + idx] = f2bf(acc[grp][ct][j]);
                        }
                    }
                }
            }
        }
    }
}

// ---------------------------------------------------------------------------
// CSR scan: blocksum -> scanfinal (inline 49-element bsum prefix).
// ---------------------------------------------------------------------------
__global__ __launch_bounds__(256) void blocksum_kernel(
    const int* __restrict__ cnt, int* __restrict__ bsum, int N)
{
    __shared__ int ws[4];
    const int tid = threadIdx.x;
    int base = blockIdx.x * 1024 + tid * 4;
    int s = 0;
    if (base + 3 < N) {
        int4 v = *reinterpret_cast<const int4*>(cnt + base);
        s = v.x + v.y + v.z + v.w;
    } else {
        for (int i = 0; i < 4; ++i)
            if (base + i < N) s += cnt[base + i];
    }
    #pragma unroll
    for (int m = 32; m >= 1; m >>= 1) s += __shfl_xor(s, m, 64);
    if ((tid & 63) == 0) ws[tid >> 6] = s;
    __syncthreads();
    if (tid == 0) bsum[blockIdx.x] = ws[0] + ws[1] + ws[2] + ws[3];
}

__global__ __launch_bounds__(256) void scanfinal_kernel(
    const int* __restrict__ cnt, const int* __restrict__ bsum,
    int* __restrict__ row_start, int* __restrict__ cursor,
    int N, int E, int NB)
{
    __shared__ int sboff;
    __shared__ int wsum[4];
    const int tid = threadIdx.x, lane = tid & 63, w = tid >> 6;

    if (tid < 64) {
        int v = (tid < NB && tid < blockIdx.x) ? bsum[tid] : 0;
        #pragma unroll
        for (int m = 32; m >= 1; m >>= 1) v += __shfl_xor(v, m, 64);
        if (tid == 0) sboff = v;
    }
    __syncthreads();

    int base = blockIdx.x * 1024 + tid * 4;
    int a0 = 0, a1 = 0, a2 = 0, a3 = 0;
    if (base + 3 < N) {
        int4 v = *reinterpret_cast<const int4*>(cnt + base);
        a0 = v.x; a1 = v.y; a2 = v.z; a3 = v.w;
    } else {
        if (base + 0 < N) a0 = cnt[base + 0];
        if (base + 1 < N) a1 = cnt[base + 1];
        if (base + 2 < N) a2 = cnt[base + 2];
        if (base + 3 < N) a3 = cnt[base + 3];
    }
    const int tsum = a0 + a1 + a2 + a3;
    int v = tsum;
    #pragma unroll
    for (int off = 1; off < 64; off <<= 1) {
        int t = __shfl_up(v, off, 64);
        if (lane >= off) v += t;
    }
    if (lane == 63) wsum[w] = v;
    __syncthreads();
    int woff = 0;
    for (int i = 0; i < w; ++i) woff += wsum[i];
    int run = sboff + woff + v - tsum;

    int r0 = run, r1 = run + a0, r2 = r1 + a1, r3 = r2 + a2;
    if (base + 3 < N) {
        int4 o = make_int4(r0, r1, r2, r3);
        *reinterpret_cast<int4*>(row_start + base) = o;
        *reinterpret_cast<int4*>(cursor + base) = o;
    } else {
        int rr[4] = {r0, r1, r2, r3};
        for (int i = 0; i < 4; ++i)
            if (base + i < N) { row_start[base + i] = rr[i]; cursor[base + i] = rr[i]; }
    }
    if (blockIdx.x == 0 && tid == 0) row_start[N] = E;
}

__global__ __launch_bounds__(256) void scatter_kernel(
    const int* __restrict__ src, const int* __restrict__ dst,
    int* __restrict__ cursor, int* __restrict__ csr_src, int E)
{
    int e = blockIdx.x * 256 + threadIdx.x;
    if (e < E) {
        int d = dst[e];
        int pos = atomicAdd(&cursor[d], 1);
        csr_src[pos] = src[e];
    }
}

// ---------------------------------------------------------------------------
// Fused score+softmax+aggregate, 32 lanes per edge, 2 edges per wave-iter.
// Lane (half=lane>>5, j=lane&31): owns cols 4j..4j+3 of edge (i+half).
// One ushort8 (16B) load per lane per edge = full 512B kv row per 32 lanes.
// Head dot: 4-lane shfl_xor(1,2) reduce. Halves combined once at the end.
// Tail masked (e *= m). csr indices prefetched 2 pairs ahead.
// ---------------------------------------------------------------------------
__global__ __launch_bounds__(256) void fused_agg_kernel(
    const unsigned short* __restrict__ qb,
    const unsigned short* __restrict__ kvb,
    const int* __restrict__ row_start, const int* __restrict__ csr_src,
    float* __restrict__ rst, int N)
{
    const int lane = threadIdx.x & 63;
    const int j = lane & 31;
    const int half = lane >> 5;
    const int node = blockIdx.x * 4 + (threadIdx.x >> 6);
    if (node >= N) return;

    const int beg = row_start[node];
    const int nE  = row_start[node + 1] - beg;
    if (nE <= 0) return;                       // rst already holds residual
    const int* cp = csr_src + beg;
    const int last = nE - 1;

    // q cols 4j..4j+3 (halves load the same address -> broadcast)
    ushort4 qraw = *reinterpret_cast<const ushort4*>(qb + (size_t)node * 128 + 4 * j);
    const float q0 = bf2f(qraw.x), q1 = bf2f(qraw.y),
                q2 = bf2f(qraw.z), q3 = bf2f(qraw.w);

    float a0 = 0.f, a1 = 0.f, a2 = 0.f, a3 = 0.f, z = 0.f;

    int sa = cp[min(half, last)];
    int sb = cp[min(half + 2, last)];

    #pragma unroll 2
    for (int i = 0; i < nE; i += 2) {
        const int ii = i + half;
        const float m = (ii < nE) ? 1.f : 0.f;
        const int scur = sa;
        sa = sb;
        sb = cp[min(ii + 4, last)];

        const unsigned short* kp = kvb + (size_t)scur * 256 + 8 * j;
        short8 kv8 = *reinterpret_cast<const short8*>(kp);
        // elems: 0,2,4,6 = k[4j..4j+3]; 1,3,5,7 = v[4j..4j+3]
        float p = q0 * bf2f((unsigned short)kv8[0])
                + q1 * bf2f((unsigned short)kv8[2])
                + q2 * bf2f((unsigned short)kv8[4])
                + q3 * bf2f((unsigned short)kv8[6]);
        p += __shfl_xor(p, 1, 64);
        p += __shfl_xor(p, 2, 64);
        float e = (p >= 0.f) ? p : NEG_SLOPE * p;
        e = m * __expf(e);
        z += e;
        a0 = fmaf(e, bf2f((unsigned short)kv8[1]), a0);
        a1 = fmaf(e, bf2f((unsigned short)kv8[3]), a1);
        a2 = fmaf(e, bf2f((unsigned short)kv8[5]), a2);
        a3 = fmaf(e, bf2f((unsigned short)kv8[7]), a3);
    }

    // combine the two halves
    a0 += __shfl_xor(a0, 32, 64);
    a1 += __shfl_xor(a1, 32, 64);
    a2 += __shfl_xor(a2, 32, 64);
    a3 += __shfl_xor(a3, 32, 64);
    z  += __shfl_xor(z, 32, 64);

    if (half == 0) {
        const size_t base = (size_t)node * 128 + 4 * j;
        float inv = 1.f / z;
        float4 rv = *reinterpret_cast<const float4*>(rst + base);
        rv.x = fmaf(a0, inv, rv.x);
        rv.y = fmaf(a1, inv, rv.y);
        rv.z = fmaf(a2, inv, rv.z);
        rv.w = fmaf(a3, inv, rv.w);
        *reinterpret_cast<float4*>(rst + base) = rv;
    }
}

extern "C" void kernel_launch(void* const* d_in, const int* in_sizes, int n_in,
                              void* d_out, int out_size, void* d_ws, size_t ws_size,
                              hipStream_t stream) {
    const float* h    = (const float*)d_in[0];
    const int*   src  = (const int*)d_in[2];
    const int*   dst  = (const int*)d_in[3];
    const float* Wq   = (const float*)d_in[4];
    const float* Wk   = (const float*)d_in[5];
    const float* Wv   = (const float*)d_in[6];
    const float* Wres = (const float*)d_in[8];
    float* rst = (float*)d_out;

    const int N = in_sizes[0] / 128;   // 50000
    const int E = in_sizes[2];         // 800000

    unsigned short* qb  = (unsigned short*)d_ws;           // N*128 bf16
    unsigned short* kvb = qb + (size_t)N * 128;            // N*256 bf16
    unsigned short* wpk = kvb + (size_t)N * 256;           // 65536 bf16
    int* cnt       = (int*)(wpk + 4 * 16384);
    int* row_start = cnt + N;          // N+1
    int* cursor    = row_start + (N + 1);
    int* csr_src   = cursor + N;
    int* bsum      = csr_src + E;

    const int n4 = N / 4;              // 12500
    const int NB = (N + 1023) / 1024;  // 49 <= 64
    const int PB = (N + 127) / 128;    // proj blocks

    zero_wconv_kernel<<<(8192 + n4 + 255) / 256, 256, 0, stream>>>(
        Wq, Wk, Wv, Wres, wpk, cnt, n4);
    proj_count_kernel<<<PB + CB, 256, 0, stream>>>(h, wpk, qb, kvb, rst,
                                                   dst, cnt, N, E, PB);
    blocksum_kernel<<<NB, 256, 0, stream>>>(cnt, bsum, N);
    scanfinal_kernel<<<NB, 256, 0, stream>>>(cnt, bsum, row_start, cursor,
                                             N, E, NB);
    scatter_kernel<<<(E + 255) / 256, 256, 0, stream>>>(src, dst, cursor,
                                                        csr_src, E);
    fused_agg_kernel<<<(N + 3) / 4, 256, 0, stream>>>(qb, kvb, row_start,
                                                      csr_src, rst, N);
}